// Round 7
// baseline (97.386 us; speedup 1.0000x reference)
//
#include <hip/hip_runtime.h>
#include <hip/hip_bf16.h>

typedef __attribute__((ext_vector_type(8))) short bf16x8;
typedef __attribute__((ext_vector_type(4))) float f32x4;

#define B_ 2048
#define S_ 200
#define D_ 128
#define H_ 64
#define NT 13
#define LOG2E 1.44269504f

// ws layout
#define WS_TA 0                       // f32 tA[2048][64]   = 512 KB
#define WS_BC (512*1024)              // f32 bcT[64][128]   = 32 KB  (W1b - W1c, transposed)
#define WS_DT (512*1024 + 32768)      // f32 dT [64][128]   = 32 KB  (W1d, transposed)

static __device__ __forceinline__ short f2bf_hw(float f) {
    return (short)__builtin_bit_cast(unsigned short, __float2bfloat16(f));  // RNE
}

// ---- prep: exact fp32 tA[b][n] = t.(W1a+W1c)+b1 ; transpose folded weights ----
__global__ __launch_bounds__(256)
void prep_kernel(const float* __restrict__ tgt, const float* __restrict__ W1,
                 const float* __restrict__ b1, char* __restrict__ ws)
{
    __shared__ float tl[16][128];
    const int tid = threadIdx.x;
    const int b0 = blockIdx.x * 16;
    for (int i = tid; i < 512; i += 256) {
        int bb = i >> 5, q = i & 31;
        *(float4*)&tl[bb][q * 4] = *(const float4*)(tgt + (size_t)(b0 + bb) * D_ + q * 4);
    }
    __syncthreads();
    const int n = tid & 63;
    const int bb0 = (tid >> 6) * 4;
    float a0 = 0.f, a1 = 0.f, a2 = 0.f, a3 = 0.f;
    for (int d = 0; d < 128; ++d) {
        float wsum = W1[d * H_ + n] + W1[(256 + d) * H_ + n];  // W1a + W1c
        a0 = fmaf(tl[bb0 + 0][d], wsum, a0);
        a1 = fmaf(tl[bb0 + 1][d], wsum, a1);
        a2 = fmaf(tl[bb0 + 2][d], wsum, a2);
        a3 = fmaf(tl[bb0 + 3][d], wsum, a3);
    }
    const float bn = b1[n];
    float* tA = (float*)(ws + WS_TA);
    tA[(size_t)(b0 + bb0 + 0) * H_ + n] = a0 + bn;
    tA[(size_t)(b0 + bb0 + 1) * H_ + n] = a1 + bn;
    tA[(size_t)(b0 + bb0 + 2) * H_ + n] = a2 + bn;
    tA[(size_t)(b0 + bb0 + 3) * H_ + n] = a3 + bn;

    if (blockIdx.x == 0) {
        float* bcT = (float*)(ws + WS_BC);
        float* dT  = (float*)(ws + WS_DT);
        for (int i = tid; i < 8192; i += 256) {
            int nn = i >> 7, k = i & 127;
            bcT[nn * 128 + k] = W1[(128 + k) * H_ + nn] - W1[(256 + k) * H_ + nn];
            dT [nn * 128 + k] = W1[(384 + k) * H_ + nn];
        }
    }
}

// ---- fused: ONE WAVE PER BATCH; barrier-free; swapped-operand MFMA flash ----
__global__ __launch_bounds__(256, 2)
void din_fused(const float* __restrict__ tgt, const float* __restrict__ hist,
               const int* __restrict__ mask, const float* __restrict__ W2,
               const char* __restrict__ ws, float* __restrict__ out)
{
    __shared__ __align__(16) char wt[4][16384];   // per-wave swizzled bf16 W''^T [n=64][k=128]

    const int tid  = threadIdx.x;
    const int lane = tid & 63;
    const int wv   = tid >> 6;
    const int b    = blockIdx.x * 4 + wv;         // one batch per wave
    const int lo   = lane & 15;
    const int hi   = lane >> 4;
    char* mywt = wt[wv];

    // ---- issue first two history tiles early (independent of the build) ----
    f32x4 stA[4][2], stB[4][2];
    int mAv, mBv;
    auto loadt = [&](f32x4 (&st)[4][2], int& mv, int t) {
        int srow = (t << 4) + lo;
        int sc = srow > S_ - 1 ? S_ - 1 : srow;
        const float* hp = hist + ((size_t)b * S_ + sc) * D_ + hi * 8;
        #pragma unroll
        for (int ks = 0; ks < 4; ++ks) {
            st[ks][0] = *(const f32x4*)(hp + ks * 32);
            st[ks][1] = *(const f32x4*)(hp + ks * 32 + 4);
        }
        mv = (srow < S_) ? mask[(size_t)b * S_ + sc] : 0;
    };
    loadt(stA, mAv, 0);
    loadt(stB, mBv, 1);

    // ---- wave-local W'' build: lane owns kb = lo (8 k's), rows n = hi*16+j ----
    // W''[k][n] = (W1b-W1c)[k][n] + t[k]*W1d[k][n], bf16, [n][k] XOR-swizzled
    {
        const float* bcT = (const float*)(ws + WS_BC);
        const float* dT  = (const float*)(ws + WS_DT);
        const int kb = lo;                        // fixed k-octet per lane
        f32x4 t0 = *(const f32x4*)(tgt + (size_t)b * D_ + kb * 8);
        f32x4 t1 = *(const f32x4*)(tgt + (size_t)b * D_ + kb * 8 + 4);
        #pragma unroll 4
        for (int j = 0; j < 16; ++j) {
            int n = hi * 16 + j;
            f32x4 bc0 = *(const f32x4*)(bcT + n * 128 + kb * 8);
            f32x4 bc1 = *(const f32x4*)(bcT + n * 128 + kb * 8 + 4);
            f32x4 dd0 = *(const f32x4*)(dT  + n * 128 + kb * 8);
            f32x4 dd1 = *(const f32x4*)(dT  + n * 128 + kb * 8 + 4);
            bf16x8 v;
            #pragma unroll
            for (int e = 0; e < 4; ++e) {
                v[e]     = f2bf_hw(fmaf(t0[e], dd0[e], bc0[e]));
                v[e + 4] = f2bf_hw(fmaf(t1[e], dd1[e], bc1[e]));
            }
            int byteoff = (n * 256 + kb * 16) ^ ((n & 7) << 4);
            *(bf16x8*)(mywt + byteoff) = v;
        }
    }
    // in-wave ds_write -> ds_read ordering is guaranteed via lgkmcnt; no barrier.

    // per-lane constants for n = ng*16 + hi*4 + e (swapped-D layout)
    f32x4 tav[4], w2v[4];
    #pragma unroll
    for (int ng = 0; ng < 4; ++ng) {
        tav[ng] = *(const f32x4*)((const float*)(ws + WS_TA) + (size_t)b * H_ + ng * 16 + hi * 4);
        f32x4 wv4 = *(const f32x4*)(W2 + ng * 16 + hi * 4);
        w2v[ng] = (f32x4){wv4[0] * LOG2E, wv4[1] * LOG2E, wv4[2] * LOG2E, wv4[3] * LOG2E};
    }

    // A-operand (W'') swizzled LDS offsets: addr = vbase[ng] + koff[ks]
    int vbase[4], koff[4];
    #pragma unroll
    for (int ng = 0; ng < 4; ++ng) vbase[ng] = (ng * 16 + lo) * 256;
    #pragma unroll
    for (int ks = 0; ks < 4; ++ks) koff[ks] = (ks * 64 + hi * 16) ^ ((lo & 7) << 4);

    float o[4][8];
    #pragma unroll
    for (int ks = 0; ks < 4; ++ks)
        #pragma unroll
        for (int e = 0; e < 8; ++e) o[ks][e] = 0.f;
    float l = 0.f, m2 = -1e30f;

    auto compt = [&](f32x4 (&st)[4][2], int mv, int t) {
        // fp32 -> bf16 B fragments (history)
        bf16x8 bfr[4];
        #pragma unroll
        for (int ks = 0; ks < 4; ++ks)
            #pragma unroll
            for (int e = 0; e < 4; ++e) {
                bfr[ks][e]     = f2bf_hw(st[ks][0][e]);
                bfr[ks][e + 4] = f2bf_hw(st[ks][1][e]);
            }
        // swapped MFMA: D[n,s]; A = W''^T frags (wave-local LDS), B = history frags
        f32x4 acc[4];
        #pragma unroll
        for (int ng = 0; ng < 4; ++ng) acc[ng] = (f32x4){0.f, 0.f, 0.f, 0.f};
        #pragma unroll
        for (int ks = 0; ks < 4; ++ks)
            #pragma unroll
            for (int ng = 0; ng < 4; ++ng) {
                bf16x8 afrag = *(const bf16x8*)(mywt + vbase[ng] + koff[ks]);
                acc[ng] = __builtin_amdgcn_mfma_f32_16x16x32_bf16(afrag, bfr[ks], acc[ng], 0, 0, 0);
            }
        // lane-local relu-dot over 16 n-values (tree to cut chain depth)
        float s0 = 0.f, s1 = 0.f, s2 = 0.f, s3 = 0.f;
        #pragma unroll
        for (int e = 0; e < 4; ++e) {
            s0 = fmaf(fmaxf(acc[0][e] + tav[0][e], 0.f), w2v[0][e], s0);
            s1 = fmaf(fmaxf(acc[1][e] + tav[1][e], 0.f), w2v[1][e], s1);
            s2 = fmaf(fmaxf(acc[2][e] + tav[2][e], 0.f), w2v[2][e], s2);
            s3 = fmaf(fmaxf(acc[3][e] + tav[3][e], 0.f), w2v[3][e], s3);
        }
        float sum = (s0 + s1) + (s2 + s3);
        // n-sum across the 4 hi groups: 2 butterflies -> uniform across hi
        sum += __shfl_xor(sum, 16);
        sum += __shfl_xor(sum, 32);
        float lg = mv ? sum : -1e30f;
        // tile max over the 16 lo-lanes -> wave-uniform
        float tm = lg;
        tm = fmaxf(tm, __shfl_xor(tm, 1));
        tm = fmaxf(tm, __shfl_xor(tm, 2));
        tm = fmaxf(tm, __shfl_xor(tm, 4));
        tm = fmaxf(tm, __shfl_xor(tm, 8));
        if (tm > m2 + 11.5f) {                 // defer-rescale (T13)
            float r = exp2f(m2 - tm);
            #pragma unroll
            for (int ks = 0; ks < 4; ++ks)
                #pragma unroll
                for (int e = 0; e < 8; ++e) o[ks][e] *= r;
            l *= r;
            m2 = tm;
        }
        float p = mv ? exp2f(lg - m2) : 0.f;
        l += p;
        #pragma unroll
        for (int ks = 0; ks < 4; ++ks) {
            o[ks][0] = fmaf(p, st[ks][0][0], o[ks][0]);
            o[ks][1] = fmaf(p, st[ks][0][1], o[ks][1]);
            o[ks][2] = fmaf(p, st[ks][0][2], o[ks][2]);
            o[ks][3] = fmaf(p, st[ks][0][3], o[ks][3]);
            o[ks][4] = fmaf(p, st[ks][1][0], o[ks][4]);
            o[ks][5] = fmaf(p, st[ks][1][1], o[ks][5]);
            o[ks][6] = fmaf(p, st[ks][1][2], o[ks][6]);
            o[ks][7] = fmaf(p, st[ks][1][3], o[ks][7]);
        }
    };

    // ---- 13-tile deep pipeline, register double-buffered ----
    #pragma unroll 1
    for (int t = 0; t < 12; t += 2) {
        compt(stA, mAv, t);
        if (t + 2 < NT) loadt(stA, mAv, t + 2);
        compt(stB, mBv, t + 1);
        if (t + 3 < NT) loadt(stB, mBv, t + 3);
    }
    compt(stA, mAv, 12);

    // deferred reduce over the 16 lo-lanes
    #pragma unroll
    for (int ks = 0; ks < 4; ++ks)
        #pragma unroll
        for (int e = 0; e < 8; ++e) {
            float v = o[ks][e];
            v += __shfl_xor(v, 1);
            v += __shfl_xor(v, 2);
            v += __shfl_xor(v, 4);
            v += __shfl_xor(v, 8);
            o[ks][e] = v;
        }
    l += __shfl_xor(l, 1);
    l += __shfl_xor(l, 2);
    l += __shfl_xor(l, 4);
    l += __shfl_xor(l, 8);

    // direct stores: lanes lo==0 hold d = ks*32 + hi*8 + e ; m2 cancels, b2 cancels
    const float inv = 1.0f / l;
    if (lo == 0) {
        float* op = out + (size_t)b * D_ + hi * 8;
        #pragma unroll
        for (int ks = 0; ks < 4; ++ks) {
            f32x4 v0 = {o[ks][0] * inv, o[ks][1] * inv, o[ks][2] * inv, o[ks][3] * inv};
            f32x4 v1 = {o[ks][4] * inv, o[ks][5] * inv, o[ks][6] * inv, o[ks][7] * inv};
            *(f32x4*)(op + ks * 32)     = v0;
            *(f32x4*)(op + ks * 32 + 4) = v1;
        }
    }
}

extern "C" void kernel_launch(void* const* d_in, const int* in_sizes, int n_in,
                              void* d_out, int out_size, void* d_ws, size_t ws_size,
                              hipStream_t stream) {
    const float* tgt  = (const float*)d_in[0];
    const float* hist = (const float*)d_in[1];
    const int*   mask = (const int*)d_in[2];
    const float* W1   = (const float*)d_in[3];
    const float* b1   = (const float*)d_in[4];
    const float* W2   = (const float*)d_in[5];
    const float* b2   = (const float*)d_in[6];
    (void)b2;  // cancels in softmax
    float* out = (float*)d_out;
    char* ws = (char*)d_ws;

    prep_kernel<<<128, 256, 0, stream>>>(tgt, W1, b1, ws);
    din_fused<<<B_ / 4, 256, 0, stream>>>(tgt, hist, mask, W2, ws, out);
}